// Round 11
// baseline (384.864 us; speedup 1.0000x reference)
//
#include <hip/hip_runtime.h>
#include <hip/hip_bf16.h>
#include <math.h>

#define T_TOK 2048
#define DM 768
#define DF 3072
#define NE 8
#define NTILES_MAX 24   // sum over experts of ceil(cnt/256) <= 4096/256 + 7 = 23

typedef __attribute__((ext_vector_type(4))) float f32x4;
typedef __attribute__((ext_vector_type(8))) short bf16x8;

static __device__ __forceinline__ ushort f2bf(float f) {
    union { float f; unsigned u; } x; x.f = f;
    unsigned r = x.u + 0x7fff + ((x.u >> 16) & 1);
    return (ushort)(r >> 16);
}
static __device__ __forceinline__ float bf2f(ushort u) {
    union { unsigned u; float f; } x; x.u = ((unsigned)u) << 16; return x.f;
}
static __device__ __forceinline__ unsigned pk2(float lo, float hi) {
    unsigned r;
    asm("v_cvt_pk_bf16_f32 %0, %1, %2" : "=v"(r) : "v"(lo), "v"(hi));
    return r;
}

// ---------------- LN + router (top-2) ----------------
__global__ __launch_bounds__(256) void ln_router_kernel(
    const float* __restrict__ hs, const float* __restrict__ gamma,
    const float* __restrict__ beta, const float* __restrict__ rw,
    ushort* __restrict__ xbf, float* __restrict__ topw, int* __restrict__ topi,
    int* __restrict__ counts)
{
    int t = blockIdx.x;
    int tid = threadIdx.x;
    const float* row = hs + (size_t)t * DM;
    float v[3];
    v[0] = row[tid]; v[1] = row[tid + 256]; v[2] = row[tid + 512];
    float s  = v[0] + v[1] + v[2];
    float sq = v[0]*v[0] + v[1]*v[1] + v[2]*v[2];
    #pragma unroll
    for (int off = 32; off > 0; off >>= 1) {
        s  += __shfl_down(s, off);
        sq += __shfl_down(sq, off);
    }
    __shared__ float wsum[4], wsq[4];
    __shared__ float pl[4][8];
    int lane = tid & 63, wv = tid >> 6;
    if (lane == 0) { wsum[wv] = s; wsq[wv] = sq; }
    __syncthreads();
    float tot  = wsum[0] + wsum[1] + wsum[2] + wsum[3];
    float totq = wsq[0] + wsq[1] + wsq[2] + wsq[3];
    float mu = tot * (1.0f / 768.0f);
    float var = totq * (1.0f / 768.0f) - mu * mu;
    float rstd = rsqrtf(var + 1e-5f);

    float p[8];
    #pragma unroll
    for (int e = 0; e < 8; e++) p[e] = 0.f;
    #pragma unroll
    for (int i = 0; i < 3; i++) {
        int d = tid + i * 256;
        float yv = (v[i] - mu) * rstd * gamma[d] + beta[d];
        xbf[(size_t)t * DM + d] = f2bf(yv);
        const float* r8 = rw + (size_t)d * 8;
        #pragma unroll
        for (int e = 0; e < 8; e++) p[e] += yv * r8[e];
    }
    #pragma unroll
    for (int off = 32; off > 0; off >>= 1) {
        #pragma unroll
        for (int e = 0; e < 8; e++) p[e] += __shfl_down(p[e], off);
    }
    if (lane == 0) {
        #pragma unroll
        for (int e = 0; e < 8; e++) pl[wv][e] = p[e];
    }
    __syncthreads();
    if (tid == 0) {
        float lg[8];
        #pragma unroll
        for (int e = 0; e < 8; e++) lg[e] = pl[0][e] + pl[1][e] + pl[2][e] + pl[3][e];
        int i0 = 0; float l0 = lg[0];
        #pragma unroll
        for (int e = 1; e < 8; e++) if (lg[e] > l0) { l0 = lg[e]; i0 = e; }
        int i1 = -1; float l1 = -3.4e38f;
        #pragma unroll
        for (int e = 0; e < 8; e++) if (e != i0 && lg[e] > l1) { l1 = lg[e]; i1 = e; }
        float w0 = 1.0f / (1.0f + __expf(l1 - l0));
        topi[2 * t] = i0;  topi[2 * t + 1] = i1;
        topw[2 * t] = w0;  topw[2 * t + 1] = 1.0f - w0;
        atomicAdd(&counts[i0], 1);
        atomicAdd(&counts[i1], 1);
    }
}

// ---------------- scan: build 256-row tile table ----------------
// ctl[0..7]=counts, [16..23]=cursors, [24]=ntiles. tiles = (expert, grow0, rows).
__global__ void scan_kernel(int* __restrict__ ctl, int4* __restrict__ tiles)
{
    if (threadIdx.x == 0 && blockIdx.x == 0) {
        int acc = 0, nt = 0;
        for (int e = 0; e < 8; e++) {
            int cnt = ctl[e];
            for (int m0 = 0; m0 < cnt && nt < NTILES_MAX; m0 += 256) {
                tiles[nt] = make_int4(e, acc + m0, min(256, cnt - m0), 0);
                nt++;
            }
            acc += cnt;
        }
        ctl[24] = nt;
    }
}

// ---------------- bucket fill ----------------
__global__ __launch_bounds__(256) void bucket_kernel(
    const int* __restrict__ topi, int* __restrict__ ctl,
    int* __restrict__ bucket_tok, int* __restrict__ tok_slot)
{
    int t = blockIdx.x * 256 + threadIdx.x;
    if (t >= T_TOK) return;
    int offs[8]; int acc = 0;
    #pragma unroll
    for (int e = 0; e < 8; e++) { offs[e] = acc; acc += ctl[e]; }
    #pragma unroll
    for (int k = 0; k < 2; k++) {
        int e = topi[2 * t + k];
        int pos = atomicAdd(&ctl[16 + e], 1);
        int idx = offs[e] + pos;
        bucket_tok[idx] = t;
        tok_slot[2 * t + k] = idx;
    }
}

// ---------------- streaming weight pack (templated N -> magic-mul div) ----------------
template<int N>
__global__ __launch_bounds__(256) void wpack_kernel(
    const float* __restrict__ src, unsigned* __restrict__ dst, int total_q)
{
    int stride = gridDim.x * 256;
    for (int i = blockIdx.x * 256 + threadIdx.x; i < total_q; i += stride) {
        unsigned o = (unsigned)i * 4;
        unsigned k2 = o / (unsigned)N;
        unsigned n  = o - k2 * (unsigned)N;
        const float* s = src + (size_t)(2 * k2) * N + n;
        float4 a = *(const float4*)s;
        float4 b = *(const float4*)(s + N);
        uint4 r;
        r.x = pk2(a.x, b.x); r.y = pk2(a.y, b.y);
        r.z = pk2(a.z, b.z); r.w = pk2(a.w, b.w);
        *(uint4*)(dst + o) = r;
    }
}

// ---------------- bucketed MFMA GEMM: 256x256 tile, 16 waves, B pair-packed -------------
// A: [M][K] bf16. Bp: [K/2][N] u32. BK=32. LDS: A [256][32]bf16 16K + B [16][256]u32 16K
// per buffer, 3-deep = 96 KiB. 1 block/CU (VGPR+LDS), 16 waves (4x4 grid, 64x64/wave).
// Counted per-wave vmcnt(2): per iter each wave stages 1 A + 1 B load for tile t+2,
// computes tile t, drains exactly tile t+1's loads; t+2 stays in flight across barrier.
// A: source k-chunk XOR swizzle; B: source col-granule XOR swizzle + xk read spread.
template<bool SILU, bool GATHER, int NT, int SPLITS>
__global__ __launch_bounds__(1024) void moe_gemm(
    const ushort* __restrict__ A, const unsigned* __restrict__ Bp,
    ushort* __restrict__ C, const int* __restrict__ ctl,
    const int* __restrict__ bucket_tok, const int4* __restrict__ tiles,
    int K, int N)
{
    int bid = blockIdx.x;
    int tl = bid % NTILES_MAX;
    int rest = bid / NTILES_MAX;
    int nt = rest % NT;
    int sk = rest / NT;
    if (tl >= ctl[24]) return;
    int4 t4 = tiles[tl];
    int e = t4.x, grow0 = t4.y, rows = t4.z;
    const int Ks = K / SPLITS;
    const int kbase = sk * Ks;

    __shared__ ushort   Al[3][256 * 32];
    __shared__ unsigned Bl[3][16 * 256];

    int tid = threadIdx.x, lane = tid & 63, wv = tid >> 6;   // wv 0..15
    // A source chunk swizzle: dest slot (lane&3) takes source chunk (lane&3)^((lane>>3)&3)
    int kchA = ((lane & 3) ^ ((lane >> 3) & 3)) * 8;

    const ushort* aptr;
    {
        int r = wv * 16 + (lane >> 2);             // 0..255
        int rr = r < rows ? r : rows - 1;
        if (GATHER) aptr = A + (size_t)bucket_tok[grow0 + rr] * K;
        else        aptr = A + (size_t)(grow0 + rr) * K;
    }
    // B staging: instruction wv covers u32-row wv (1024B); lane granule 4*lane,
    // source col-granule XOR-swizzled by ((row&7)<<2).
    const unsigned* Bb = Bp + (size_t)e * ((size_t)N * (K / 2));
    int n0 = nt * 256;
    int bscol = (4 * lane) ^ ((wv & 7) << 2);

    f32x4 acc[4][4];
    #pragma unroll
    for (int m = 0; m < 4; m++)
        #pragma unroll
        for (int n = 0; n < 4; n++)
            acc[m][n] = (f32x4){0.f, 0.f, 0.f, 0.f};

    int wr = wv >> 2, wc = wv & 3;                 // wave grid 4x4
    int l15 = lane & 15, kq = lane >> 4;
    int xk = (kq & 1) << 4;

    auto stage = [&](int buf, int k0) {
        __builtin_amdgcn_global_load_lds(
            (const __attribute__((address_space(1))) void*)(aptr + k0 + kchA),
            (__attribute__((address_space(3))) void*)(&Al[buf][(wv * 16) * 32 + lane * 8]),
            16, 0, 0);
        int k2b = k0 >> 1;
        __builtin_amdgcn_global_load_lds(
            (const __attribute__((address_space(1))) void*)(Bb + (size_t)(k2b + wv) * N + n0 + bscol),
            (__attribute__((address_space(3))) void*)(&Bl[buf][wv * 256 + lane * 4]),
            16, 0, 0);
    };
    auto compute = [&](int cur) {
        bf16x8 af[4], bfr[4];
        #pragma unroll
        for (int m = 0; m < 4; m++) {
            int row = wr * 64 + m * 16 + l15;
            af[m] = *(const bf16x8*)&Al[cur][row * 32 + ((kq ^ ((row >> 1) & 3)) << 3)];
        }
        const unsigned* Blc = &Bl[cur][0];
        #pragma unroll
        for (int n = 0; n < 4; n++) {
            int ncol = wc * 64 + n * 16 + l15;
            union { uint4 u; bf16x8 h; } cvu;
            cvu.u.x = Blc[(kq * 4 + 0) * 256 + (ncol ^ (xk | 0))];
            cvu.u.y = Blc[(kq * 4 + 1) * 256 + (ncol ^ (xk | 4))];
            cvu.u.z = Blc[(kq * 4 + 2) * 256 + (ncol ^ (xk | 8))];
            cvu.u.w = Blc[(kq * 4 + 3) * 256 + (ncol ^ (xk | 12))];
            bfr[n] = cvu.h;
        }
        __builtin_amdgcn_s_setprio(1);
        #pragma unroll
        for (int m = 0; m < 4; m++)
            #pragma unroll
            for (int n = 0; n < 4; n++)
                acc[m][n] = __builtin_amdgcn_mfma_f32_16x16x32_bf16(af[m], bfr[n], acc[m][n], 0, 0, 0);
        __builtin_amdgcn_s_setprio(0);
    };

    const int nk = Ks >> 5;   // 24 (GEMM1) / 48 (GEMM2, splits=2) — divisible by 3

    // prologue: tiles 0,1 staged (2 loads each per wave); drain tile 0 -> vmcnt(2)
    stage(0, kbase);
    stage(1, kbase + 32);
    asm volatile("s_waitcnt vmcnt(2)" ::: "memory");
    __builtin_amdgcn_s_barrier();

    #define BODY(T, CUR, STG) { \
        int t_ = (T); \
        bool more2 = (t_ + 2 < nk); \
        if (more2) stage(STG, kbase + (t_ + 2) * 32); \
        compute(CUR); \
        if (t_ + 1 < nk) { \
            if (more2) asm volatile("s_waitcnt vmcnt(2)" ::: "memory"); \
            else       asm volatile("s_waitcnt vmcnt(0)" ::: "memory"); \
            __builtin_amdgcn_s_barrier(); \
        } \
    }

    for (int t = 0; t < nk; t += 3) {
        BODY(t,     0, 2);
        BODY(t + 1, 1, 0);
        BODY(t + 2, 2, 1);
    }
    #undef BODY

    // epilogue: row = (lane>>4)*4 + jj, col = lane&15
    #pragma unroll
    for (int m = 0; m < 4; m++) {
        #pragma unroll
        for (int n = 0; n < 4; n++) {
            #pragma unroll
            for (int jj = 0; jj < 4; jj++) {
                int r = wr * 64 + m * 16 + kq * 4 + jj;
                if (r < rows) {
                    float v = acc[m][n][jj];
                    if (SILU) v = v / (1.0f + __expf(-v));
                    int col = n0 + wc * 64 + n * 16 + l15;
                    C[((size_t)sk * (T_TOK * 2) + grow0 + r) * N + col] = f2bf(v);
                }
            }
        }
    }
}

// ---------------- combine: out = residual + w0*sum_s y0_s + w1*sum_s y1_s ----------------
template<int SPLITS>
__global__ __launch_bounds__(256) void combine_kernel(
    const float* __restrict__ hs, const ushort* __restrict__ Yp,
    const float* __restrict__ topw, const int* __restrict__ tok_slot,
    float* __restrict__ out)
{
    int t = blockIdx.x, tid = threadIdx.x;
    int s0 = tok_slot[2 * t], s1 = tok_slot[2 * t + 1];
    float w0 = topw[2 * t], w1 = topw[2 * t + 1];
    const float* h = hs + (size_t)t * DM;
    float* o = out + (size_t)t * DM;
    #pragma unroll
    for (int i = 0; i < 3; i++) {
        int d = tid + i * 256;
        float y0 = 0.f, y1 = 0.f;
        #pragma unroll
        for (int s = 0; s < SPLITS; s++) {
            y0 += bf2f(Yp[((size_t)s * (T_TOK * 2) + s0) * DM + d]);
            y1 += bf2f(Yp[((size_t)s * (T_TOK * 2) + s1) * DM + d]);
        }
        o[d] = h[d] + w0 * y0 + w1 * y1;
    }
}

extern "C" void kernel_launch(void* const* d_in, const int* in_sizes, int n_in,
                              void* d_out, int out_size, void* d_ws, size_t ws_size,
                              hipStream_t stream)
{
    const float* hs    = (const float*)d_in[0];
    const float* gamma = (const float*)d_in[1];
    const float* beta  = (const float*)d_in[2];
    const float* rw    = (const float*)d_in[3];
    const float* w1    = (const float*)d_in[4];
    const float* w2    = (const float*)d_in[5];
    float* out = (float*)d_out;
    char* ws = (char*)d_ws;

    size_t o = 0;
    auto alc = [&](size_t b) { size_t r = o; o += (b + 255) & ~255ULL; return r; };
    int*      ctl        = (int*)(ws + alc(256));
    int4*     tiles      = (int4*)(ws + alc(NTILES_MAX * 16));
    float*    topw       = (float*)(ws + alc((size_t)T_TOK * 2 * 4));
    int*      topi       = (int*)(ws + alc((size_t)T_TOK * 2 * 4));
    int*      tok_slot   = (int*)(ws + alc((size_t)T_TOK * 2 * 4));
    int*      bucket_tok = (int*)(ws + alc((size_t)T_TOK * 2 * 4));
    ushort*   xbf        = (ushort*)(ws + alc((size_t)T_TOK * DM * 2));
    unsigned* w1p        = (unsigned*)(ws + alc((size_t)NE * DF * DM * 2));
    unsigned* w2p        = (unsigned*)(ws + alc((size_t)NE * DF * DM * 2));
    ushort*   Hg         = (ushort*)(ws + alc((size_t)T_TOK * 2 * DF * 2));
    size_t yp_off        = alc((size_t)2 * T_TOK * 2 * DM * 2);
    ushort*   Yp         = (ushort*)(ws + yp_off);
    bool can_split       = (o <= ws_size);

    const int WQ = NE * DM * DF / 8;

    hipMemsetAsync(ctl, 0, 256, stream);
    ln_router_kernel<<<T_TOK, 256, 0, stream>>>(hs, gamma, beta, rw, xbf, topw, topi, ctl);
    wpack_kernel<DF><<<2048, 256, 0, stream>>>(w1, w1p, WQ);
    wpack_kernel<DM><<<2048, 256, 0, stream>>>(w2, w2p, WQ);
    scan_kernel<<<1, 64, 0, stream>>>(ctl, tiles);
    bucket_kernel<<<8, 256, 0, stream>>>(topi, ctl, bucket_tok, tok_slot);

    moe_gemm<true, true, 12, 1><<<NTILES_MAX * 12, 1024, 0, stream>>>(
        xbf, w1p, Hg, ctl, bucket_tok, tiles, DM, DF);

    if (can_split) {
        moe_gemm<false, false, 3, 2><<<NTILES_MAX * 3 * 2, 1024, 0, stream>>>(
            Hg, w2p, Yp, ctl, bucket_tok, tiles, DF, DM);
        combine_kernel<2><<<T_TOK, 256, 0, stream>>>(hs, Yp, topw, tok_slot, out);
    } else {
        moe_gemm<false, false, 3, 1><<<NTILES_MAX * 3, 1024, 0, stream>>>(
            Hg, w2p, Yp, ctl, bucket_tok, tiles, DF, DM);
        combine_kernel<1><<<T_TOK, 256, 0, stream>>>(hs, Yp, topw, tok_slot, out);
    }
}

// Round 12
// 251.634 us; speedup vs baseline: 1.5295x; 1.5295x over previous
//
#include <hip/hip_runtime.h>
#include <hip/hip_bf16.h>
#include <math.h>

#define T_TOK 2048
#define DM 768
#define DF 3072
#define NE 8
#define NTILES_MAX 24   // sum over experts of ceil(cnt/256) <= 16 + 7 = 23
#define WB1 1024        // wpack(w1) blocks fused into LN dispatch (256 thr)
#define WB2 512         // wpack(w2) blocks fused into GEMM1 dispatch (1024 thr)

typedef __attribute__((ext_vector_type(4))) float f32x4;
typedef __attribute__((ext_vector_type(8))) short bf16x8;

static __device__ __forceinline__ ushort f2bf(float f) {
    union { float f; unsigned u; } x; x.f = f;
    unsigned r = x.u + 0x7fff + ((x.u >> 16) & 1);
    return (ushort)(r >> 16);
}
static __device__ __forceinline__ float bf2f(ushort u) {
    union { unsigned u; float f; } x; x.u = ((unsigned)u) << 16; return x.f;
}
static __device__ __forceinline__ unsigned pk2(float lo, float hi) {
    unsigned r;
    asm("v_cvt_pk_bf16_f32 %0, %1, %2" : "=v"(r) : "v"(lo), "v"(hi));
    return r;
}

// ---------------- streaming weight pack body (device helper) ----------------
// fp32 [RT][N] -> u32 bf16-pair [RT/2][N]: out[k2][n] = bf16(W[2k2][n]) | bf16(W[2k2+1][n])<<16
template<int N>
static __device__ void wpack_body(const float* __restrict__ src, unsigned* __restrict__ dst,
                                  int total_q, int start, int stride)
{
    for (int i = start; i < total_q; i += stride) {
        unsigned o = (unsigned)i * 4;
        unsigned k2 = o / (unsigned)N;         // compile-time N -> magic multiply
        unsigned n  = o - k2 * (unsigned)N;
        const float* s = src + (size_t)(2 * k2) * N + n;
        float4 a = *(const float4*)s;
        float4 b = *(const float4*)(s + N);
        uint4 r;
        r.x = pk2(a.x, b.x); r.y = pk2(a.y, b.y);
        r.z = pk2(a.z, b.z); r.w = pk2(a.w, b.w);
        *(uint4*)(dst + o) = r;
    }
}

// ---------------- LN + router (top-2), with fused wpack(w1) role-split blocks ----------
__global__ __launch_bounds__(256) void ln_router_kernel(
    const float* __restrict__ hs, const float* __restrict__ gamma,
    const float* __restrict__ beta, const float* __restrict__ rw,
    ushort* __restrict__ xbf, float* __restrict__ topw, int* __restrict__ topi,
    int* __restrict__ counts,
    const float* __restrict__ w1, unsigned* __restrict__ w1p, int wq)
{
    if (blockIdx.x >= T_TOK) {
        int wb = blockIdx.x - T_TOK;
        wpack_body<DF>(w1, w1p, wq, wb * 256 + threadIdx.x, WB1 * 256);
        return;
    }
    int t = blockIdx.x;
    int tid = threadIdx.x;
    const float* row = hs + (size_t)t * DM;
    float v[3];
    v[0] = row[tid]; v[1] = row[tid + 256]; v[2] = row[tid + 512];
    float s  = v[0] + v[1] + v[2];
    float sq = v[0]*v[0] + v[1]*v[1] + v[2]*v[2];
    #pragma unroll
    for (int off = 32; off > 0; off >>= 1) {
        s  += __shfl_down(s, off);
        sq += __shfl_down(sq, off);
    }
    __shared__ float wsum[4], wsq[4];
    __shared__ float pl[4][8];
    int lane = tid & 63, wv = tid >> 6;
    if (lane == 0) { wsum[wv] = s; wsq[wv] = sq; }
    __syncthreads();
    float tot  = wsum[0] + wsum[1] + wsum[2] + wsum[3];
    float totq = wsq[0] + wsq[1] + wsq[2] + wsq[3];
    float mu = tot * (1.0f / 768.0f);
    float var = totq * (1.0f / 768.0f) - mu * mu;
    float rstd = rsqrtf(var + 1e-5f);

    float p[8];
    #pragma unroll
    for (int e = 0; e < 8; e++) p[e] = 0.f;
    #pragma unroll
    for (int i = 0; i < 3; i++) {
        int d = tid + i * 256;
        float yv = (v[i] - mu) * rstd * gamma[d] + beta[d];
        xbf[(size_t)t * DM + d] = f2bf(yv);
        const float* r8 = rw + (size_t)d * 8;
        #pragma unroll
        for (int e = 0; e < 8; e++) p[e] += yv * r8[e];
    }
    #pragma unroll
    for (int off = 32; off > 0; off >>= 1) {
        #pragma unroll
        for (int e = 0; e < 8; e++) p[e] += __shfl_down(p[e], off);
    }
    if (lane == 0) {
        #pragma unroll
        for (int e = 0; e < 8; e++) pl[wv][e] = p[e];
    }
    __syncthreads();
    if (tid == 0) {
        float lg[8];
        #pragma unroll
        for (int e = 0; e < 8; e++) lg[e] = pl[0][e] + pl[1][e] + pl[2][e] + pl[3][e];
        int i0 = 0; float l0 = lg[0];
        #pragma unroll
        for (int e = 1; e < 8; e++) if (lg[e] > l0) { l0 = lg[e]; i0 = e; }
        int i1 = -1; float l1 = -3.4e38f;
        #pragma unroll
        for (int e = 0; e < 8; e++) if (e != i0 && lg[e] > l1) { l1 = lg[e]; i1 = e; }
        float w0 = 1.0f / (1.0f + __expf(l1 - l0));
        topi[2 * t] = i0;  topi[2 * t + 1] = i1;
        topw[2 * t] = w0;  topw[2 * t + 1] = 1.0f - w0;
        atomicAdd(&counts[i0], 1);
        atomicAdd(&counts[i1], 1);
    }
}

// ---------------- scan: build 256-row tile table ----------------
__global__ void scan_kernel(int* __restrict__ ctl, int4* __restrict__ tiles)
{
    if (threadIdx.x == 0 && blockIdx.x == 0) {
        int acc = 0, nt = 0;
        for (int e = 0; e < 8; e++) {
            int cnt = ctl[e];
            for (int m0 = 0; m0 < cnt && nt < NTILES_MAX; m0 += 256) {
                tiles[nt] = make_int4(e, acc + m0, min(256, cnt - m0), 0);
                nt++;
            }
            acc += cnt;
        }
        ctl[24] = nt;
    }
}

// ---------------- bucket fill ----------------
__global__ __launch_bounds__(256) void bucket_kernel(
    const int* __restrict__ topi, int* __restrict__ ctl,
    int* __restrict__ bucket_tok, int* __restrict__ tok_slot)
{
    int t = blockIdx.x * 256 + threadIdx.x;
    if (t >= T_TOK) return;
    int offs[8]; int acc = 0;
    #pragma unroll
    for (int e = 0; e < 8; e++) { offs[e] = acc; acc += ctl[e]; }
    #pragma unroll
    for (int k = 0; k < 2; k++) {
        int e = topi[2 * t + k];
        int pos = atomicAdd(&ctl[16 + e], 1);
        int idx = offs[e] + pos;
        bucket_tok[idx] = t;
        tok_slot[2 * t + k] = idx;
    }
}

// ---------------- bucketed MFMA GEMM: 256x256 tile, 16 waves, B pair-packed -------------
// A: [M][K] bf16. Bp: [K/2][N] u32. BK=32. LDS 2-deep: 2*(16K A + 16K B) = 64 KiB
// -> 2 blocks/CU, 32 waves/CU (VGPR ~64). Per iter: stage(t+1) [2 loads/wave],
// compute(t) [16 MFMA], vmcnt(0)+barrier; partner block covers the drain.
// Optional fused role: blocks past the GEMM grid run wpack(w2) streaming (idle CUs).
template<bool SILU, bool GATHER, int NT, int SPLITS, bool FUSE_WPACK>
__global__ __launch_bounds__(1024) void moe_gemm(
    const ushort* __restrict__ A, const unsigned* __restrict__ Bp,
    ushort* __restrict__ C, const int* __restrict__ ctl,
    const int* __restrict__ bucket_tok, const int4* __restrict__ tiles,
    int K, int N,
    const float* __restrict__ wsrc, unsigned* __restrict__ wdst, int wq)
{
    int bid = blockIdx.x;
    const int GBASE = NTILES_MAX * NT * SPLITS;
    if (FUSE_WPACK && bid >= GBASE) {
        int wb = bid - GBASE;
        wpack_body<DM>(wsrc, wdst, wq, wb * 1024 + (int)threadIdx.x, WB2 * 1024);
        return;
    }
    int tl = bid % NTILES_MAX;
    int rest = bid / NTILES_MAX;
    int nt = rest % NT;
    int sk = rest / NT;
    if (tl >= ctl[24]) return;
    int4 t4 = tiles[tl];
    int e = t4.x, grow0 = t4.y, rows = t4.z;
    const int Ks = K / SPLITS;
    const int kbase = sk * Ks;

    __shared__ ushort   Al[2][256 * 32];
    __shared__ unsigned Bl[2][16 * 256];

    int tid = threadIdx.x, lane = tid & 63, wv = tid >> 6;   // wv 0..15
    int kchA = ((lane & 3) ^ ((lane >> 3) & 3)) * 8;

    const ushort* aptr;
    {
        int r = wv * 16 + (lane >> 2);             // 0..255
        int rr = r < rows ? r : rows - 1;
        if (GATHER) aptr = A + (size_t)bucket_tok[grow0 + rr] * K;
        else        aptr = A + (size_t)(grow0 + rr) * K;
    }
    const unsigned* Bb = Bp + (size_t)e * ((size_t)N * (K / 2));
    int n0 = nt * 256;
    int bscol = (4 * lane) ^ ((wv & 7) << 2);

    f32x4 acc[4][4];
    #pragma unroll
    for (int m = 0; m < 4; m++)
        #pragma unroll
        for (int n = 0; n < 4; n++)
            acc[m][n] = (f32x4){0.f, 0.f, 0.f, 0.f};

    int wr = wv >> 2, wc = wv & 3;                 // wave grid 4x4
    int l15 = lane & 15, kq = lane >> 4;
    int xk = (kq & 1) << 4;

    auto stage = [&](int buf, int k0) {
        __builtin_amdgcn_global_load_lds(
            (const __attribute__((address_space(1))) void*)(aptr + k0 + kchA),
            (__attribute__((address_space(3))) void*)(&Al[buf][(wv * 16) * 32 + lane * 8]),
            16, 0, 0);
        int k2b = k0 >> 1;
        __builtin_amdgcn_global_load_lds(
            (const __attribute__((address_space(1))) void*)(Bb + (size_t)(k2b + wv) * N + n0 + bscol),
            (__attribute__((address_space(3))) void*)(&Bl[buf][wv * 256 + lane * 4]),
            16, 0, 0);
    };
    auto compute = [&](int cur) {
        bf16x8 af[4], bfr[4];
        #pragma unroll
        for (int m = 0; m < 4; m++) {
            int row = wr * 64 + m * 16 + l15;
            af[m] = *(const bf16x8*)&Al[cur][row * 32 + ((kq ^ ((row >> 1) & 3)) << 3)];
        }
        const unsigned* Blc = &Bl[cur][0];
        #pragma unroll
        for (int n = 0; n < 4; n++) {
            int ncol = wc * 64 + n * 16 + l15;
            union { uint4 u; bf16x8 h; } cvu;
            cvu.u.x = Blc[(kq * 4 + 0) * 256 + (ncol ^ (xk | 0))];
            cvu.u.y = Blc[(kq * 4 + 1) * 256 + (ncol ^ (xk | 4))];
            cvu.u.z = Blc[(kq * 4 + 2) * 256 + (ncol ^ (xk | 8))];
            cvu.u.w = Blc[(kq * 4 + 3) * 256 + (ncol ^ (xk | 12))];
            bfr[n] = cvu.h;
        }
        __builtin_amdgcn_s_setprio(1);
        #pragma unroll
        for (int m = 0; m < 4; m++)
            #pragma unroll
            for (int n = 0; n < 4; n++)
                acc[m][n] = __builtin_amdgcn_mfma_f32_16x16x32_bf16(af[m], bfr[n], acc[m][n], 0, 0, 0);
        __builtin_amdgcn_s_setprio(0);
    };

    const int nk = Ks >> 5;

    stage(0, kbase);
    asm volatile("s_waitcnt vmcnt(0)" ::: "memory");
    __builtin_amdgcn_s_barrier();

    for (int ks = 0; ks < nk; ks++) {
        int cur = ks & 1;
        if (ks + 1 < nk) stage(cur ^ 1, kbase + (ks + 1) * 32);
        compute(cur);
        asm volatile("s_waitcnt vmcnt(0)" ::: "memory");
        __builtin_amdgcn_s_barrier();
    }

    // epilogue: row = (lane>>4)*4 + jj, col = lane&15
    #pragma unroll
    for (int m = 0; m < 4; m++) {
        #pragma unroll
        for (int n = 0; n < 4; n++) {
            #pragma unroll
            for (int jj = 0; jj < 4; jj++) {
                int r = wr * 64 + m * 16 + kq * 4 + jj;
                if (r < rows) {
                    float v = acc[m][n][jj];
                    if (SILU) v = v / (1.0f + __expf(-v));
                    int col = n0 + wc * 64 + n * 16 + l15;
                    C[((size_t)sk * (T_TOK * 2) + grow0 + r) * N + col] = f2bf(v);
                }
            }
        }
    }
}

// ---------------- combine: out = residual + w0*sum_s y0_s + w1*sum_s y1_s ----------------
template<int SPLITS>
__global__ __launch_bounds__(256) void combine_kernel(
    const float* __restrict__ hs, const ushort* __restrict__ Yp,
    const float* __restrict__ topw, const int* __restrict__ tok_slot,
    float* __restrict__ out)
{
    int t = blockIdx.x, tid = threadIdx.x;
    int s0 = tok_slot[2 * t], s1 = tok_slot[2 * t + 1];
    float w0 = topw[2 * t], w1 = topw[2 * t + 1];
    const float* h = hs + (size_t)t * DM;
    float* o = out + (size_t)t * DM;
    #pragma unroll
    for (int i = 0; i < 3; i++) {
        int d = tid + i * 256;
        float y0 = 0.f, y1 = 0.f;
        #pragma unroll
        for (int s = 0; s < SPLITS; s++) {
            y0 += bf2f(Yp[((size_t)s * (T_TOK * 2) + s0) * DM + d]);
            y1 += bf2f(Yp[((size_t)s * (T_TOK * 2) + s1) * DM + d]);
        }
        o[d] = h[d] + w0 * y0 + w1 * y1;
    }
}

extern "C" void kernel_launch(void* const* d_in, const int* in_sizes, int n_in,
                              void* d_out, int out_size, void* d_ws, size_t ws_size,
                              hipStream_t stream)
{
    const float* hs    = (const float*)d_in[0];
    const float* gamma = (const float*)d_in[1];
    const float* beta  = (const float*)d_in[2];
    const float* rw    = (const float*)d_in[3];
    const float* w1    = (const float*)d_in[4];
    const float* w2    = (const float*)d_in[5];
    float* out = (float*)d_out;
    char* ws = (char*)d_ws;

    size_t o = 0;
    auto alc = [&](size_t b) { size_t r = o; o += (b + 255) & ~255ULL; return r; };
    int*      ctl        = (int*)(ws + alc(256));
    int4*     tiles      = (int4*)(ws + alc(NTILES_MAX * 16));
    float*    topw       = (float*)(ws + alc((size_t)T_TOK * 2 * 4));
    int*      topi       = (int*)(ws + alc((size_t)T_TOK * 2 * 4));
    int*      tok_slot   = (int*)(ws + alc((size_t)T_TOK * 2 * 4));
    int*      bucket_tok = (int*)(ws + alc((size_t)T_TOK * 2 * 4));
    ushort*   xbf        = (ushort*)(ws + alc((size_t)T_TOK * DM * 2));
    unsigned* w1p        = (unsigned*)(ws + alc((size_t)NE * DF * DM * 2));
    unsigned* w2p        = (unsigned*)(ws + alc((size_t)NE * DF * DM * 2));
    ushort*   Hg         = (ushort*)(ws + alc((size_t)T_TOK * 2 * DF * 2));
    size_t yp_off        = alc((size_t)4 * T_TOK * 2 * DM * 2);
    ushort*   Yp         = (ushort*)(ws + yp_off);
    bool can_split       = (o <= ws_size);

    const int WQ = NE * DM * DF / 8;   // uint4 quads per weight matrix

    hipMemsetAsync(ctl, 0, 256, stream);
    // LN + router, with wpack(w1) fused on extra blocks
    ln_router_kernel<<<T_TOK + WB1, 256, 0, stream>>>(
        hs, gamma, beta, rw, xbf, topw, topi, ctl, w1, w1p, WQ);
    scan_kernel<<<1, 64, 0, stream>>>(ctl, tiles);
    bucket_kernel<<<8, 256, 0, stream>>>(topi, ctl, bucket_tok, tok_slot);

    // GEMM1 (+ wpack(w2) fused on extra blocks)
    moe_gemm<true, true, 12, 1, true><<<NTILES_MAX * 12 + WB2, 1024, 0, stream>>>(
        xbf, w1p, Hg, ctl, bucket_tok, tiles, DM, DF, w2, w2p, WQ);

    if (can_split) {
        moe_gemm<false, false, 3, 4, false><<<NTILES_MAX * 3 * 4, 1024, 0, stream>>>(
            Hg, w2p, Yp, ctl, bucket_tok, tiles, DF, DM, nullptr, nullptr, 0);
        combine_kernel<4><<<T_TOK, 256, 0, stream>>>(hs, Yp, topw, tok_slot, out);
    } else {
        moe_gemm<false, false, 3, 1, false><<<NTILES_MAX * 3, 1024, 0, stream>>>(
            Hg, w2p, Yp, ctl, bucket_tok, tiles, DF, DM, nullptr, nullptr, 0);
        combine_kernel<1><<<T_TOK, 256, 0, stream>>>(hs, Yp, topw, tok_slot, out);
    }
}